// Round 7
// baseline (240.607 us; speedup 1.0000x reference)
//
#include <hip/hip_runtime.h>
#include <stdint.h>

// Problem constants (fixed by the reference):
#define N_ROWS 262144
#define DIM    128
#define HID    16
#define NEXP   21
// Segments of 64 rows, each expert's region padded up to a multiple of 64.
#define NSEG   (N_ROWS / 64 + NEXP)   // 4096 + 21 = 4117 worst case
#define NBLK1  256                    // blocks for hist/scatter
#define RPB    (N_ROWS / NBLK1)       // 1024 rows per block
#define RPT    (RPB / 256)            // 4 rows per thread

// k_main LDS: 64 row-slots x 512 B, NO pad (stride 512 so one all-lane DMA
// covers two whole rows).  Bank spread comes from the xor chunk swizzle:
// slot s stores global chunk c at offset (c ^ (s&31))*16, so readback step c
// hits banks 4*((c^L)&7) across lanes -> 8 dwords/bank = wave64 minimum.
#define BLK_LDS  (64 * 512)           // 32768 B -> 5 blocks (waves) per CU

// ---------------------------------------------------------------------------
// K1: per-block histogram of sid + reserve per-(block,expert) ranges.
// ---------------------------------------------------------------------------
__global__ __launch_bounds__(256) void k_hist(const int* __restrict__ sid,
                                              int* __restrict__ counts,
                                              int* __restrict__ blockBase) {
    __shared__ int lh[NEXP];
    int t = threadIdx.x;
    if (t < NEXP) lh[t] = 0;
    __syncthreads();
    int base = blockIdx.x * RPB + t;
#pragma unroll
    for (int r = 0; r < RPT; r++) {
        atomicAdd(&lh[sid[base + r * 256]], 1);
    }
    __syncthreads();
    if (t < NEXP) blockBase[blockIdx.x * NEXP + t] = atomicAdd(&counts[t], lh[t]);
}

// ---------------------------------------------------------------------------
// K2: scatter rows into per-expert 64-padded buckets.  Entry = row | (e<<24).
// Tail slots stay -1 (memset 0xFF).
// ---------------------------------------------------------------------------
__global__ __launch_bounds__(256) void k_scatter(const int* __restrict__ sid,
                                                 const int* __restrict__ counts,
                                                 const int* __restrict__ blockBase,
                                                 int* __restrict__ buckets) {
    __shared__ int sbase[NEXP];
    __shared__ int lcur[NEXP];
    int t = threadIdx.x;
    if (t == 0) {
        int acc = 0;
        for (int e = 0; e < NEXP; e++) {
            sbase[e] = acc + blockBase[blockIdx.x * NEXP + e];
            acc += ((counts[e] + 63) >> 6) << 6;   // pad each expert to 64
        }
    }
    if (t < NEXP) lcur[t] = 0;
    __syncthreads();
    int base = blockIdx.x * RPB + t;
#pragma unroll
    for (int r = 0; r < RPT; r++) {
        int row = base + r * 256;
        int e = sid[row];
        int lp = atomicAdd(&lcur[e], 1);
        buckets[sbase[e] + lp] = row | (e << 24);
    }
}

// ---------------------------------------------------------------------------
// K3 (round 7): one 64-thread block (one wave) per same-expert segment.
//
// Burst staging (tests the DRAM page-reopen theory): instruction p stages
// slots 2p (lanes 0-31) and 2p+1 (lanes 32-63) -- each row's full 512 B
// (4 consecutive 128-B lines) in ONE all-lane global_load_lds_dwordx4, LDS
// dest = p*1024 + lane*16 (contiguous; matches the wave-uniform-base +
// lane x size DMA semantics, all lanes active = the r4/r5-proven shape).
// Every prior round fetched a row's 4 lines ~2000 cyc apart and plateaued
// at ~2.0 TB/s while sequential fills hit 6.9 TB/s (~4x = per-line page
// reopen); whole-row bursts should restore most of that factor.
//
// Compute = r5's correctness-verified scheme: per phase q (32 features),
// wq[m] = w1[q*512 + m*64 + lane] (coalesced), FMA operand via
// readlane(wq[m], 16t+j) (m,t,j compile-time; q rolled for I$).
// ---------------------------------------------------------------------------
typedef __attribute__((address_space(1))) const uint32_t gu32;
typedef __attribute__((address_space(3))) uint32_t lu32;

__device__ __forceinline__ void stage16(const float* gp, char* lp) {
    __builtin_amdgcn_global_load_lds((gu32*)(uintptr_t)gp,
                                     (lu32*)(uintptr_t)lp, 16, 0, 0);
}

__device__ __forceinline__ float bcast(float v, int srclane) {
    return __uint_as_float(__builtin_amdgcn_readlane(__float_as_uint(v), srclane));
}

__global__ __launch_bounds__(64, 1) void k_main6(const float* __restrict__ x,
                                                 const float* __restrict__ W1,
                                                 const float* __restrict__ b1,
                                                 const float* __restrict__ W2,
                                                 const float* __restrict__ b2,
                                                 const int* __restrict__ buckets,
                                                 float* __restrict__ out) {
    __shared__ char lds[BLK_LDS];
    const int seg = blockIdx.x;
    const int lane = threadIdx.x;                  // one wave per block
    int ent = buckets[seg * 64 + lane];
    if (__ballot(ent >= 0) == 0ULL) return;        // wholly-empty tail segment
    // Valid slots form a prefix -> lane 0 valid -> e is wave-uniform.
    const int e = __builtin_amdgcn_readfirstlane(ent) >> 24;
    const int row = ent & 0x00FFFFFF;
    const int vrow = (ent >= 0) ? row : 0;         // invalid lanes: dup row 0

    // ---- burst staging: 32 all-lane DMAs, each = two whole 512-B rows ----
    const int half = lane >> 5;                    // 0: slot 2p, 1: slot 2p+1
    const int c32 = lane & 31;
#pragma unroll
    for (int p = 0; p < 32; p++) {
        const int slot = 2 * p + half;
        const int rowp = __shfl(vrow, slot, 64);           // slot's global row
        const int chunk = c32 ^ (slot & 31);               // xor bank swizzle
        const float* gp = x + (size_t)(unsigned)rowp * DIM + chunk * 4;
        stage16(gp, lds + p * 1024 + lane * 16);
    }

    float h[HID];
#pragma unroll
    for (int j = 0; j < HID; j++) h[j] = b1[e * HID + j];

    __builtin_amdgcn_s_waitcnt(0);                 // all staging visible

    // ---- compute: lane L processes slot L; r5-verified wq broadcast ----
    const float* __restrict__ w1 = W1 + e * (DIM * HID);
    const char* rowbase = lds + lane * 512;
    const int sL = lane & 31;

#pragma unroll 1
    for (int q = 0; q < 4; q++) {                  // 4 phases x 32 features
        // this phase's 512 W1 values across the wave (L2-hot, coalesced)
        const float* __restrict__ w1q = w1 + q * 512;
        float wq[8];
#pragma unroll
        for (int m = 0; m < 8; m++) wq[m] = w1q[m * 64 + lane];
#pragma unroll
        for (int m = 0; m < 8; m++) {
            const int c = q * 8 + m;               // global 16-B chunk index
            const float4 xv = *(const float4*)(rowbase + (((c ^ sL) & 31) << 4));
            const float xc[4] = {xv.x, xv.y, xv.z, xv.w};
#pragma unroll
            for (int t = 0; t < 4; t++) {
#pragma unroll
                for (int j = 0; j < HID; j++)
                    h[j] = fmaf(xc[t], bcast(wq[m], t * 16 + j), h[j]);
            }
        }
    }

    float acc = b2[e];
#pragma unroll
    for (int j = 0; j < HID; j++) acc = fmaf(fmaxf(h[j], 0.0f), W2[e * HID + j], acc);
    if (ent >= 0) out[row] = fmaxf(acc, 0.0f);
}

// ---------------------------------------------------------------------------
// Fallback (only if ws_size is too small for the buckets): thread-per-row.
// ---------------------------------------------------------------------------
__global__ __launch_bounds__(256) void k_naive(const float* __restrict__ x,
                                               const int* __restrict__ sid,
                                               const float* __restrict__ W1,
                                               const float* __restrict__ b1,
                                               const float* __restrict__ W2,
                                               const float* __restrict__ b2,
                                               float* __restrict__ out) {
    int row = blockIdx.x * 256 + threadIdx.x;
    if (row >= N_ROWS) return;
    int e = sid[row];
    const float* w1 = W1 + e * (DIM * HID);
    const float* xr = x + (size_t)row * DIM;
    float h[HID];
#pragma unroll
    for (int j = 0; j < HID; j++) h[j] = b1[e * HID + j];
    for (int k = 0; k < DIM; k++) {
        float xk = xr[k];
#pragma unroll
        for (int j = 0; j < HID; j++) h[j] = fmaf(xk, w1[k * HID + j], h[j]);
    }
    float acc = b2[e];
#pragma unroll
    for (int j = 0; j < HID; j++) acc = fmaf(fmaxf(h[j], 0.0f), W2[e * HID + j], acc);
    out[row] = fmaxf(acc, 0.0f);
}

extern "C" void kernel_launch(void* const* d_in, const int* in_sizes, int n_in,
                              void* d_out, int out_size, void* d_ws, size_t ws_size,
                              hipStream_t stream) {
    const float* x   = (const float*)d_in[0];
    const int*   sid = (const int*)d_in[1];
    const float* W1  = (const float*)d_in[2];
    const float* b1  = (const float*)d_in[3];
    const float* W2  = (const float*)d_in[4];
    const float* b2  = (const float*)d_in[5];
    float* out = (float*)d_out;

    // Workspace layout: buckets | counts(32) | blockBase(NBLK1*NEXP)
    const size_t bucketBytes = (size_t)NSEG * 64 * sizeof(int);
    const size_t countBytes  = 32 * sizeof(int);
    const size_t bbBytes     = (size_t)NBLK1 * NEXP * sizeof(int);
    const size_t need = bucketBytes + countBytes + bbBytes;

    if (ws_size < need) {
        k_naive<<<(N_ROWS + 255) / 256, 256, 0, stream>>>(x, sid, W1, b1, W2, b2, out);
        return;
    }

    char* ws = (char*)d_ws;
    int* buckets   = (int*)ws;
    int* counts    = (int*)(ws + bucketBytes);
    int* blockBase = (int*)(ws + bucketBytes + countBytes);

    hipMemsetAsync(buckets, 0xFF, bucketBytes, stream);   // all -1
    hipMemsetAsync(counts, 0, countBytes, stream);
    k_hist<<<NBLK1, 256, 0, stream>>>(sid, counts, blockBase);
    k_scatter<<<NBLK1, 256, 0, stream>>>(sid, counts, blockBase, buckets);
    k_main6<<<NSEG, 64, 0, stream>>>(x, W1, b1, W2, b2, buckets, out);
}